// Round 1
// baseline (480.713 us; speedup 1.0000x reference)
//
#include <hip/hip_runtime.h>
#include <hip/hip_cooperative_groups.h>
#include <stdint.h>

namespace cg = cooperative_groups;

#define NN 8192
#define K_ORD 262144u      // ordered top-k positions (off-diagonal, both triangles)
#define TIE_CAP 16384u

// ws layout (uint32 words):
// [0..3071]    partial counts: round r (0..2) block bx(<512) writes [r*1024 + bx]
//              (bx = probe*2 + half; per-probe count = sum of its 2 slots)
// [4096] hi  [4097] lo  [4098] r_ord  [4099] tie_cnt  [4100..4103] pad
// [4104..12295] sorted p values (8192 floats, desc by key)
// [12296..]    tie entries: uint2 {key, flat_idx} (12296 even -> 8B aligned)
#define WS_HI 4096
#define WS_LO 4097
#define WS_R 4098
#define WS_TIECNT 4099
#define WS_STATE0 4096
#define WS_STATEN 8
#define WS_SORT 4104
#define WS_TIE 12296

__device__ __forceinline__ uint32_t fkey(float x) {
    // order-preserving map float -> uint32 (neg: ~u, pos: u|0x80000000)
    uint32_t u = __float_as_uint(x);
    uint32_t m = (uint32_t)((int32_t)u >> 31) | 0x80000000u;
    return u ^ m;
}
__device__ __forceinline__ float inv_fkey(uint32_t k) {
    uint32_t u = (k & 0x80000000u) ? (k ^ 0x80000000u) : ~k;
    return __uint_as_float(u);
}

// ---------------------------------------------------------------------------
// Partial f(T) over rows [a0, a0+2048): 4 INDEPENDENT interleaved 14-step
// chains per thread (ILP4; correctness-proven R6/R9/R13). Search space [0,8192].
// Verbatim from the 7-kernel version.
__device__ uint32_t eval_count4(const float* __restrict__ ps, uint32_t T, int a0) {
    const int a = a0 + threadIdx.x * 4;
    float pa[4];
    uint32_t neg[4];
    int pos[4] = {0, 0, 0, 0};
#pragma unroll
    for (int c = 0; c < 4; ++c) {
        pa[c] = ps[a + c];
        neg[c] = __float_as_uint(pa[c]) >> 31;
    }
#pragma unroll
    for (int st = NN; st > 0; st >>= 1) {
#pragma unroll
        for (int c = 0; c < 4; ++c) {
            const int cand = pos[c] + st;
            if (cand <= NN) {
                const uint32_t pr = (fkey(pa[c] * ps[cand - 1]) > T) ? 1u : 0u;
                if (pr ^ neg[c]) pos[c] = cand;
            }
        }
    }
    uint32_t cnt = 0;
#pragma unroll
    for (int c = 0; c < 4; ++c) {
        uint32_t cc = neg[c] ? (uint32_t)(NN - pos[c]) : (uint32_t)pos[c];
        cc -= (fkey(pa[c] * pa[c]) > T) ? 1u : 0u;   // exclude diagonal pairing
        cnt += cc;
    }
    return cnt;
}

// Aggregate round r's 512 partials (2 slots per probe) -> update bracket.
// All 512 threads participate; every block computes the same result.
// Agent-scope atomic loads: slots were written by other blocks (other XCDs)
// within this same kernel, so L1/L2 bypass is required for visibility.
__device__ __forceinline__ void agg_round(const uint32_t* __restrict__ ws, int r,
                                          uint32_t* __restrict__ sh,
                                          uint32_t& lo, uint32_t& hi,
                                          uint32_t& fstar) {
    const int tx = threadIdx.x;
    uint32_t flag = 1024u;
    if (tx < 256) {
        const uint32_t c =
            __hip_atomic_load(&ws[r * 1024 + tx * 2], __ATOMIC_RELAXED,
                              __HIP_MEMORY_SCOPE_AGENT) +
            __hip_atomic_load(&ws[r * 1024 + tx * 2 + 1], __ATOMIC_RELAXED,
                              __HIP_MEMORY_SCOPE_AGENT);
        if (c < K_ORD) flag = (uint32_t)tx;
    }
    sh[tx] = flag;
    __syncthreads();
    for (int off = 256; off > 0; off >>= 1) {
        if (tx < off) sh[tx] = min(sh[tx], sh[tx + off]);
        __syncthreads();
    }
    const uint32_t cs = sh[0];   // minimal c with f(T_c) < K (exists: f(hi)<K)
    __syncthreads();
    fstar = __hip_atomic_load(&ws[r * 1024 + cs * 2], __ATOMIC_RELAXED,
                              __HIP_MEMORY_SCOPE_AGENT) +
            __hip_atomic_load(&ws[r * 1024 + cs * 2 + 1], __ATOMIC_RELAXED,
                              __HIP_MEMORY_SCOPE_AGENT);
    const uint64_t W = (uint64_t)(hi - lo);
    const uint32_t Tc = lo + (uint32_t)(((uint64_t)(cs + 1) * W) >> 8);
    if (cs > 0) lo = lo + (uint32_t)(((uint64_t)cs * W) >> 8) + 1u;
    hi = Tc;
}

// ---------------------------------------------------------------------------
// Fused cooperative selection: sort + 3 probe rounds + finalize in ONE kernel.
// 512 blocks x 512 threads. LDS = 32KB key/value union + 2KB reduce = 34KB.
// __launch_bounds__(512,4): VGPR<=128 -> >=2 blocks/CU by VGPR, 4 by LDS ->
// 512 blocks co-resident (cooperative launch fits exactly).
__global__ void __launch_bounds__(512, 4)
fused_select_kernel(const float* __restrict__ p, uint32_t* __restrict__ ws) {
    __shared__ uint32_t ks[NN];          // phase A: keys; phase B+: sorted floats
    __shared__ uint32_t sh[512];
    float* ps = reinterpret_cast<float*>(ks);
    const int tx = threadIdx.x;
    const int bx = blockIdx.x;
    cg::grid_group grid = cg::this_grid();

    // --- Phase A: state zero + brute-force rank sort (16 elems per block) ---
    if (bx == 0 && tx < WS_STATEN) ws[WS_STATE0 + tx] = 0u;
    for (int t = tx; t < NN / 4; t += 512) {
        const float4 v = reinterpret_cast<const float4*>(p)[t];
        reinterpret_cast<uint4*>(ks)[t] =
            make_uint4(fkey(v.x), fkey(v.y), fkey(v.z), fkey(v.w));
    }
    __syncthreads();
    {
        const int e = bx * 16 + (tx >> 5);
        const int seg = tx & 31;
        const uint32_t ke = ks[e];
        uint32_t cnt = 0;
        for (int it = 0; it < 256; ++it) {
            const int j = seg + 32 * it;
            const uint32_t kj = ks[j];
            cnt += (kj > ke) ? 1u : 0u;
            cnt += (kj == ke && j < e) ? 1u : 0u;
        }
        for (int off = 16; off > 0; off >>= 1) cnt += __shfl_down(cnt, off, 32);
        if (seg == 0) {
            // agent-scope store: read by all blocks (all XCDs) after grid.sync
            __hip_atomic_store(reinterpret_cast<float*>(ws + WS_SORT) + cnt,
                               inv_fkey(ke), __ATOMIC_RELAXED,
                               __HIP_MEMORY_SCOPE_AGENT);
        }
    }
    grid.sync();

    // --- Phase B: stage sorted values to LDS once (reused by all 3 rounds) ---
    for (int t = tx; t < NN / 4; t += 512)
        reinterpret_cast<float4*>(ps)[t] =
            reinterpret_cast<const float4*>(ws + WS_SORT)[t];
    __syncthreads();

    const int probe = bx >> 1;     // 256 probes, 2 blocks each
    const int half = bx & 1;       // rows [half*4096, half*4096+4096)
    uint32_t lo = 0u, hi = 0xFFFFFFFFu, fstar = 0u;

    // --- Rounds 0..2: probe 256 thresholds, narrow bracket 256x per round ---
    for (int r = 0; r < 3; ++r) {
        if (r > 0) agg_round(ws, r - 1, sh, lo, hi, fstar);
        const uint64_t W = (uint64_t)(hi - lo);
        const uint32_t T = lo + (uint32_t)(((uint64_t)(probe + 1) * W) >> 8);
        const uint32_t cnt = eval_count4(ps, T, half * 4096) +
                             eval_count4(ps, T, half * 4096 + 2048);
        __syncthreads();
        sh[tx] = cnt;
        __syncthreads();
        for (int off = 256; off > 0; off >>= 1) {
            if (tx < off) sh[tx] += sh[tx + off];
            __syncthreads();
        }
        if (tx == 0)
            __hip_atomic_store(&ws[r * 1024 + bx], sh[0], __ATOMIC_RELAXED,
                               __HIP_MEMORY_SCOPE_AGENT);
        grid.sync();
    }

    // --- Finalize: aggregate round 2 -> bracket <= 257 keys wide ---
    agg_round(ws, 2, sh, lo, hi, fstar);
    if (bx == 0 && tx == 0) {
        ws[WS_HI] = hi;               // f(hi) < K
        ws[WS_LO] = lo;               // f(lo-1) >= K  (K-th key in [lo,hi])
        ws[WS_R] = K_ORD - fstar;     // in-bracket slots, by (key desc, idx asc)
    }
}

// ---------------------------------------------------------------------------
// Kernel 2 (R11-verbatim): streamed 268MB mask write, plain float4 stores.
// 1.0 iff key > hi; lo <= key <= hi -> tie buffer {key, flat}.
__global__ void __launch_bounds__(256) mask_kernel(const float* __restrict__ p,
                                                   float* __restrict__ out,
                                                   uint32_t* __restrict__ ws) {
    const int tx = threadIdx.x;
    const int i = blockIdx.y;
    const int jb0 = blockIdx.x * 4096;
    const uint32_t hi = ws[WS_HI];
    const uint32_t lo = ws[WS_LO];
    const float pi = p[i];
    const size_t rowbase = (size_t)i * NN;
#pragma unroll
    for (int q = 0; q < 4; ++q) {
        const int j = jb0 + q * 1024 + tx * 4;
        const float4 pj = *reinterpret_cast<const float4*>(p + j);
        const float pjv[4] = {pj.x, pj.y, pj.z, pj.w};
        float vv[4];
#pragma unroll
        for (int c = 0; c < 4; ++c) {
            const int jj = j + c;
            float v = 0.0f;
            if (jj != i) {
                const uint32_t key = fkey(pi * pjv[c]);
                if (key > hi) {
                    v = 1.0f;
                } else if (key >= lo) {
                    const uint32_t pos = atomicAdd(&ws[WS_TIECNT], 1u);
                    if (pos < TIE_CAP)
                        reinterpret_cast<uint2*>(ws + WS_TIE)[pos] =
                            make_uint2(key, (uint32_t)(i * NN + jj));
                }
            }
            vv[c] = v;
        }
        float4 o;
        o.x = vv[0]; o.y = vv[1]; o.z = vv[2]; o.w = vv[3];
        *reinterpret_cast<float4*>(out + rowbase + j) = o;
    }
}

// Kernel 3 (R11-verbatim): among the n in-bracket entries set the top r by
// (key desc, flat idx asc) to 1.0 — exactly jax.lax.top_k's ordering.
__global__ void __launch_bounds__(256) tie_select_kernel(float* __restrict__ out,
                                                         uint32_t* __restrict__ ws) {
    uint32_t n = ws[WS_TIECNT];
    if (n > TIE_CAP) n = TIE_CAP;
    const uint32_t r = ws[WS_R];
    const uint2* buf = reinterpret_cast<const uint2*>(ws + WS_TIE);
    for (uint32_t e = threadIdx.x; e < n; e += 256) {
        const uint2 me = buf[e];
        uint32_t rank = 0;
        for (uint32_t m = 0; m < n; ++m) {
            const uint2 o = buf[m];
            rank += ((o.x > me.x) || (o.x == me.x && o.y < me.y)) ? 1u : 0u;
        }
        if (rank < r) out[me.y] = 1.0f;
    }
}

extern "C" void kernel_launch(void* const* d_in, const int* in_sizes, int n_in,
                              void* d_out, int out_size, void* d_ws, size_t ws_size,
                              hipStream_t stream) {
    const float* p = (const float*)d_in[0];
    float* out = (float*)d_out;
    uint32_t* ws = (uint32_t*)d_ws;

    void* args[2] = {(void*)&p, (void*)&ws};
    (void)hipLaunchCooperativeKernel(
        reinterpret_cast<const void*>(&fused_select_kernel), dim3(512),
        dim3(512), args, 0u, stream);
    mask_kernel<<<dim3(2, NN), 256, 0, stream>>>(p, out, ws);
    tie_select_kernel<<<1, 256, 0, stream>>>(out, ws);
}

// Round 2
// 340.421 us; speedup vs baseline: 1.4121x; 1.4121x over previous
//
#include <hip/hip_runtime.h>
#include <stdint.h>

#define NN 8192
#define K_ORD 262144u      // ordered top-k positions (off-diagonal, both triangles)
#define TIE_CAP 16384u

typedef float f32x4 __attribute__((ext_vector_type(4)));

// ws layout (uint32 words):
// [0..3071]    partial counts: round r (1..3) block bx writes [(r-1)*1024 + bx]
//              (bx = probe*4 + quarter; per-probe count = sum of its 4 slots)
// [4096] hi  [4097] lo  [4098] r_ord  [4099] tie_cnt  [4100..4103] pad
// [4104..12295] sorted p values (8192 floats, desc by key)
// [12296..]    tie entries: uint2 {key, flat_idx} (12296 even -> 8B aligned)
#define WS_HI 4096
#define WS_LO 4097
#define WS_R 4098
#define WS_TIECNT 4099
#define WS_STATE0 4096
#define WS_STATEN 8
#define WS_SORT 4104
#define WS_TIE 12296

__device__ __forceinline__ uint32_t fkey(float x) {
    // order-preserving map float -> uint32 (neg: ~u, pos: u|0x80000000)
    uint32_t u = __float_as_uint(x);
    uint32_t m = (uint32_t)((int32_t)u >> 31) | 0x80000000u;
    return u ^ m;
}
__device__ __forceinline__ float inv_fkey(uint32_t k) {
    uint32_t u = (k & 0x80000000u) ? (k ^ 0x80000000u) : ~k;
    return __uint_as_float(u);
}

// ---------------------------------------------------------------------------
// Kernel 1 (R8-verbatim): brute-force rank sort of p (desc by key, ties by
// index) -> ws sorted. 1024 blocks x 256 thr; block ranks 8 elements.
__global__ void __launch_bounds__(256) sort_kernel(const float* __restrict__ p,
                                                   uint32_t* __restrict__ ws) {
    __shared__ uint32_t ks[NN];
    const int tx = threadIdx.x;
    if (blockIdx.x == 0 && tx < WS_STATEN) ws[WS_STATE0 + tx] = 0u;
    for (int t = tx; t < NN / 4; t += 256) {
        const float4 v = reinterpret_cast<const float4*>(p)[t];
        reinterpret_cast<uint4*>(ks)[t] =
            make_uint4(fkey(v.x), fkey(v.y), fkey(v.z), fkey(v.w));
    }
    __syncthreads();
    const int e = blockIdx.x * 8 + (tx >> 5);
    const int seg = tx & 31;
    const uint32_t ke = ks[e];
    uint32_t cnt = 0;
    for (int it = 0; it < 256; ++it) {
        const int j = seg + 32 * it;
        const uint32_t kj = ks[j];
        cnt += (kj > ke) ? 1u : 0u;
        cnt += (kj == ke && j < e) ? 1u : 0u;
    }
    for (int off = 16; off > 0; off >>= 1) cnt += __shfl_down(cnt, off, 32);
    if (seg == 0)
        reinterpret_cast<float*>(ws + WS_SORT)[cnt] = inv_fkey(ke);  // unique rank
}

// ---------------------------------------------------------------------------
// Monotone predicate over j in [0,NN]; q(0)==1; boundary pos = max{j: q(j)}.
// q(j) = [fkey(pa*ps[j-1]) > T] ^ neg  is non-increasing in j (ps sorted desc
// numerically; product monotone in ps[j-1] with sign given by neg).
__device__ __forceinline__ uint32_t qprobe(const float* __restrict__ ps, uint32_t T,
                                           float pa, uint32_t neg, int j) {
    if (j == 0) return 1u;
    return (uint32_t)((fkey(pa * ps[j - 1]) > T) ? 1u : 0u) ^ neg;
}

// Exponential (galloping) search for the boundary from hint h in [0,NN].
// Correct for ANY hint (direction test first), fast when |pos-h| is small.
__device__ __forceinline__ int gallop_pos(const float* __restrict__ ps, uint32_t T,
                                          float pa, uint32_t neg, int h) {
    int A, B;
    if (h < NN && qprobe(ps, T, pa, neg, h + 1)) {
        // pos >= h+1: gallop up. invariant: q(A)==1, pos in [A,B]
        A = h + 1; B = NN;
        int d = 1;
        while (A < B) {
            const int m = (A + d < B) ? (A + d) : B;
            if (qprobe(ps, T, pa, neg, m)) { A = m; d <<= 1; }
            else { B = m - 1; break; }
        }
    } else {
        // pos <= h: gallop down. invariant: pos in [A,B]
        A = 0; B = h;
        int d = 1;
        while (A < B) {
            const int m = (B - d > A) ? (B - d) : A;
            if (!qprobe(ps, T, pa, neg, m)) { B = m - 1; d <<= 1; }
            else { A = m; break; }
        }
    }
    while (A < B) {   // binary search the narrowed bracket
        const int mid = (A + B + 1) >> 1;
        if (qprobe(ps, T, pa, neg, mid)) A = mid; else B = mid - 1;
    }
    return A;
}

// Partial f(T) over rows [a0, a0+2048). Chain 0: fixed 14-step binary search
// (R6/R9/R13-proven form). Chains 1..3 handle CONSECUTIVE sorted elements, so
// their boundaries are within ~1-2 of pos0 on average -> gallop from pos0.
// LDS reads/thread: 56 -> ~26.
__device__ uint32_t eval_count4(const float* __restrict__ ps, uint32_t T, int a0) {
    const int a = a0 + threadIdx.x * 4;
    float pa[4];
    uint32_t neg[4];
#pragma unroll
    for (int c = 0; c < 4; ++c) {
        pa[c] = ps[a + c];
        neg[c] = __float_as_uint(pa[c]) >> 31;
    }
    int pos[4];
    {   // chain 0: full search over [0, NN]
        int p0 = 0;
#pragma unroll
        for (int st = NN; st > 0; st >>= 1) {
            const int cand = p0 + st;
            if (cand <= NN) {
                const uint32_t pr = (fkey(pa[0] * ps[cand - 1]) > T) ? 1u : 0u;
                if (pr ^ neg[0]) p0 = cand;
            }
        }
        pos[0] = p0;
    }
#pragma unroll
    for (int c = 1; c < 4; ++c)
        pos[c] = gallop_pos(ps, T, pa[c], neg[c], pos[0]);
    uint32_t cnt = 0;
#pragma unroll
    for (int c = 0; c < 4; ++c) {
        uint32_t cc = neg[c] ? (uint32_t)(NN - pos[c]) : (uint32_t)pos[c];
        cc -= (fkey(pa[c] * pa[c]) > T) ? 1u : 0u;   // exclude diagonal pairing
        cnt += cc;
    }
    return cnt;
}

// Recompute bracket after `rounds` completed rounds (R8-proven). Per-probe
// count = sum of its 4 quarter slots (relaxed agent atomic loads).
// On exit: T* in [lo,hi], fstar = f(hi) < K.
template <int NT>
__device__ void bracket_chain(const uint32_t* __restrict__ ws, int rounds,
                              uint32_t* __restrict__ sh,
                              uint32_t& lo, uint32_t& hi, uint32_t& fstar) {
    const int tx = threadIdx.x;
    lo = 0u; hi = 0xFFFFFFFFu; fstar = 0u;
    for (int r = 0; r < rounds; ++r) {
        uint32_t flag = 1024u;
        if (tx < 256) {
            uint32_t c = 0;
#pragma unroll
            for (int q = 0; q < 4; ++q)
                c += __hip_atomic_load(&ws[r * 1024 + tx * 4 + q],
                                       __ATOMIC_RELAXED, __HIP_MEMORY_SCOPE_AGENT);
            if (c < K_ORD) flag = (uint32_t)tx;
        }
        sh[tx] = flag;
        __syncthreads();
        for (int off = NT / 2; off > 0; off >>= 1) {
            if (tx < off) sh[tx] = min(sh[tx], sh[tx + off]);
            __syncthreads();
        }
        const uint32_t cs = sh[0];   // minimal c with f(T_c) < K (exists: f(hi)<K)
        __syncthreads();
        uint32_t fsum = 0;
#pragma unroll
        for (int q = 0; q < 4; ++q)
            fsum += __hip_atomic_load(&ws[r * 1024 + cs * 4 + q],
                                      __ATOMIC_RELAXED, __HIP_MEMORY_SCOPE_AGENT);
        fstar = fsum;
        const uint64_t W = (uint64_t)(hi - lo);
        const uint32_t Tc = lo + (uint32_t)(((uint64_t)(cs + 1) * W) >> 8);
        if (cs > 0) lo = lo + (uint32_t)(((uint64_t)cs * W) >> 8) + 1u;
        hi = Tc;
    }
}

// Kernels 2-4: rounds 1-3 (R13 structure; gallop eval, plain-store partials).
template <int ROUND>
__global__ void __launch_bounds__(512) select_round_kernel(uint32_t* __restrict__ ws) {
    __shared__ float ps[NN];
    __shared__ uint32_t sh[512];
    const int tx = threadIdx.x;
    const int bx = blockIdx.x;
    for (int t = tx; t < NN / 4; t += 512)
        reinterpret_cast<float4*>(ps)[t] =
            reinterpret_cast<const float4*>(ws + WS_SORT)[t];
    __syncthreads();
    uint32_t lo, hi, fs;
    bracket_chain<512>(ws, ROUND - 1, sh, lo, hi, fs);
    const uint64_t W = (uint64_t)(hi - lo);
    const uint32_t T = lo + (uint32_t)(((uint64_t)((bx >> 2) + 1) * W) >> 8);
    const uint32_t cnt = eval_count4(ps, T, (bx & 3) * 2048);
    __syncthreads();
    sh[tx] = cnt;
    __syncthreads();
    for (int off = 256; off > 0; off >>= 1) {
        if (tx < off) sh[tx] += sh[tx + off];
        __syncthreads();
    }
    if (tx == 0) ws[(ROUND - 1) * 1024 + bx] = sh[0];   // private slot, plain store
}

// Kernel 5 (R11-verbatim): finalize after 3 rounds. Bracket <= 257 keys wide;
// whole bracket = tie class (~100-ish pairs).
__global__ void __launch_bounds__(256) finalize3_kernel(uint32_t* __restrict__ ws) {
    __shared__ uint32_t sh[256];
    uint32_t lo, hi, fs;
    bracket_chain<256>(ws, 3, sh, lo, hi, fs);
    if (threadIdx.x == 0) {
        ws[WS_HI] = hi;               // f(hi) < K
        ws[WS_LO] = lo;               // f(lo-1) >= K  (K-th key in [lo,hi])
        ws[WS_R] = K_ORD - fs;        // in-bracket slots, by (key desc, idx asc)
    }
}

// Kernel 6: streamed 268MB mask write, nontemporal float4 stores (out is
// write-once; bypass L2). 1.0 iff key > hi; lo <= key <= hi -> tie buffer.
__global__ void __launch_bounds__(256) mask_kernel(const float* __restrict__ p,
                                                   float* __restrict__ out,
                                                   uint32_t* __restrict__ ws) {
    const int tx = threadIdx.x;
    const int i = blockIdx.y;
    const int jb0 = blockIdx.x * 4096;
    const uint32_t hi = ws[WS_HI];
    const uint32_t lo = ws[WS_LO];
    const float pi = p[i];
    const size_t rowbase = (size_t)i * NN;
#pragma unroll
    for (int q = 0; q < 4; ++q) {
        const int j = jb0 + q * 1024 + tx * 4;
        const float4 pj = *reinterpret_cast<const float4*>(p + j);
        const float pjv[4] = {pj.x, pj.y, pj.z, pj.w};
        float vv[4];
#pragma unroll
        for (int c = 0; c < 4; ++c) {
            const int jj = j + c;
            float v = 0.0f;
            if (jj != i) {
                const uint32_t key = fkey(pi * pjv[c]);
                if (key > hi) {
                    v = 1.0f;
                } else if (key >= lo) {
                    const uint32_t pos = atomicAdd(&ws[WS_TIECNT], 1u);
                    if (pos < TIE_CAP)
                        reinterpret_cast<uint2*>(ws + WS_TIE)[pos] =
                            make_uint2(key, (uint32_t)(i * NN + jj));
                }
            }
            vv[c] = v;
        }
        f32x4 o;
        o.x = vv[0]; o.y = vv[1]; o.z = vv[2]; o.w = vv[3];
        __builtin_nontemporal_store(o,
            reinterpret_cast<f32x4*>(out + rowbase + j));
    }
}

// Kernel 7 (R11-verbatim): among the n in-bracket entries set the top r by
// (key desc, flat idx asc) to 1.0 — exactly jax.lax.top_k's ordering.
__global__ void __launch_bounds__(256) tie_select_kernel(float* __restrict__ out,
                                                         uint32_t* __restrict__ ws) {
    uint32_t n = ws[WS_TIECNT];
    if (n > TIE_CAP) n = TIE_CAP;
    const uint32_t r = ws[WS_R];
    const uint2* buf = reinterpret_cast<const uint2*>(ws + WS_TIE);
    for (uint32_t e = threadIdx.x; e < n; e += 256) {
        const uint2 me = buf[e];
        uint32_t rank = 0;
        for (uint32_t m = 0; m < n; ++m) {
            const uint2 o = buf[m];
            rank += ((o.x > me.x) || (o.x == me.x && o.y < me.y)) ? 1u : 0u;
        }
        if (rank < r) out[me.y] = 1.0f;
    }
}

extern "C" void kernel_launch(void* const* d_in, const int* in_sizes, int n_in,
                              void* d_out, int out_size, void* d_ws, size_t ws_size,
                              hipStream_t stream) {
    const float* p = (const float*)d_in[0];
    float* out = (float*)d_out;
    uint32_t* ws = (uint32_t*)d_ws;

    sort_kernel<<<1024, 256, 0, stream>>>(p, ws);
    select_round_kernel<1><<<1024, 512, 0, stream>>>(ws);
    select_round_kernel<2><<<1024, 512, 0, stream>>>(ws);
    select_round_kernel<3><<<1024, 512, 0, stream>>>(ws);
    finalize3_kernel<<<1, 256, 0, stream>>>(ws);
    mask_kernel<<<dim3(2, NN), 256, 0, stream>>>(p, out, ws);
    tie_select_kernel<<<1, 256, 0, stream>>>(out, ws);
}

// Round 3
// 325.555 us; speedup vs baseline: 1.4766x; 1.0457x over previous
//
#include <hip/hip_runtime.h>
#include <stdint.h>

#define NN 8192
#define K_ORD 262144u      // ordered top-k positions (off-diagonal, both triangles)
#define TIE_CAP 16384u

typedef float f32x4 __attribute__((ext_vector_type(4)));

// ws layout (uint32 words):
// [0..767]     per-probe counts: round r (0..2) probe c -> ws[r*256 + c].
//              4 quarter-blocks atomicAdd into the slot (device-scope);
//              slots zeroed by sort_kernel block 0. [768..1023] pad (zeroed).
// [4096..4103] state: [4099] tie_cnt, rest legacy/pad (zeroed by sort)
// [4104..12295] sorted p values (8192 floats, desc by key)
// [12296..]    tie entries: uint2 {key, flat_idx} (12296 even -> 8B aligned)
#define WS_TIECNT 4099
#define WS_STATE0 4096
#define WS_STATEN 8
#define WS_SORT 4104
#define WS_TIE 12296

__device__ __forceinline__ uint32_t fkey(float x) {
    // order-preserving map float -> uint32 (neg: ~u, pos: u|0x80000000)
    uint32_t u = __float_as_uint(x);
    uint32_t m = (uint32_t)((int32_t)u >> 31) | 0x80000000u;
    return u ^ m;
}
__device__ __forceinline__ float inv_fkey(uint32_t k) {
    uint32_t u = (k & 0x80000000u) ? (k ^ 0x80000000u) : ~k;
    return __uint_as_float(u);
}

// ---------------------------------------------------------------------------
// Kernel 1: brute-force rank sort of p (desc by key, ties by index) -> ws.
// 1024 blocks x 256 thr; block ranks 8 elements. Scan via ds_read_b128
// (uint4 = 4 keys/read: 256 b32 iters -> 64 b128 iters, ~3 cyc/key vs 6).
__global__ void __launch_bounds__(256) sort_kernel(const float* __restrict__ p,
                                                   uint32_t* __restrict__ ws) {
    __shared__ uint32_t ks[NN];
    const int tx = threadIdx.x;
    if (blockIdx.x == 0) {
        for (int t = tx; t < 1024; t += 256) ws[t] = 0u;       // probe count slots
        if (tx < WS_STATEN) ws[WS_STATE0 + tx] = 0u;           // state (tie_cnt)
    }
    for (int t = tx; t < NN / 4; t += 256) {
        const float4 v = reinterpret_cast<const float4*>(p)[t];
        reinterpret_cast<uint4*>(ks)[t] =
            make_uint4(fkey(v.x), fkey(v.y), fkey(v.z), fkey(v.w));
    }
    __syncthreads();
    const int e = blockIdx.x * 8 + (tx >> 5);
    const int seg = tx & 31;
    const uint32_t ke = ks[e];
    const uint4* k4 = reinterpret_cast<const uint4*>(ks);
    uint32_t cnt = 0;
    for (int it = 0; it < 64; ++it) {
        const int t4 = seg + 32 * it;     // lanes read consecutive 16B: conflict-free
        const uint4 kj = k4[t4];
        const int j = t4 * 4;
        cnt += (kj.x > ke) ? 1u : 0u; cnt += (kj.x == ke && (j + 0) < e) ? 1u : 0u;
        cnt += (kj.y > ke) ? 1u : 0u; cnt += (kj.y == ke && (j + 1) < e) ? 1u : 0u;
        cnt += (kj.z > ke) ? 1u : 0u; cnt += (kj.z == ke && (j + 2) < e) ? 1u : 0u;
        cnt += (kj.w > ke) ? 1u : 0u; cnt += (kj.w == ke && (j + 3) < e) ? 1u : 0u;
    }
    for (int off = 16; off > 0; off >>= 1) cnt += __shfl_down(cnt, off, 32);
    if (seg == 0)
        reinterpret_cast<float*>(ws + WS_SORT)[cnt] = inv_fkey(ke);  // unique rank
}

// ---------------------------------------------------------------------------
// Partial f(T) over rows [a0, a0+2048): 4 INDEPENDENT interleaved 14-step
// chains per thread (ILP4; R6/R9/R13-proven, branchless — R2's gallop variant
// was +12us from divergence; large-stride probes are LDS broadcasts = free).
__device__ uint32_t eval_count4(const float* __restrict__ ps, uint32_t T, int a0) {
    const int a = a0 + threadIdx.x * 4;
    float pa[4];
    uint32_t neg[4];
    int pos[4] = {0, 0, 0, 0};
#pragma unroll
    for (int c = 0; c < 4; ++c) {
        pa[c] = ps[a + c];
        neg[c] = __float_as_uint(pa[c]) >> 31;
    }
#pragma unroll
    for (int st = NN; st > 0; st >>= 1) {
#pragma unroll
        for (int c = 0; c < 4; ++c) {
            const int cand = pos[c] + st;
            if (cand <= NN) {
                const uint32_t pr = (fkey(pa[c] * ps[cand - 1]) > T) ? 1u : 0u;
                if (pr ^ neg[c]) pos[c] = cand;
            }
        }
    }
    uint32_t cnt = 0;
#pragma unroll
    for (int c = 0; c < 4; ++c) {
        uint32_t cc = neg[c] ? (uint32_t)(NN - pos[c]) : (uint32_t)pos[c];
        cc -= (fkey(pa[c] * pa[c]) > T) ? 1u : 0u;   // exclude diagonal pairing
        cnt += cc;
    }
    return cnt;
}

// Recompute bracket after `rounds` completed rounds. Per-probe count is ONE
// word (quarters atomicAdd'ed it). Wave-shfl min-reduce: 2 barriers/round
// instead of ~11. sh needs only 8 words. On exit: T* in [lo,hi], fstar=f(hi)<K.
template <int NT>
__device__ void bracket_chain(const uint32_t* __restrict__ ws, int rounds,
                              uint32_t* __restrict__ sh,
                              uint32_t& lo, uint32_t& hi, uint32_t& fstar) {
    const int tx = threadIdx.x;
    lo = 0u; hi = 0xFFFFFFFFu; fstar = 0u;
    for (int r = 0; r < rounds; ++r) {
        uint32_t flag = 1024u;
        if (tx < 256) {
            const uint32_t c = __hip_atomic_load(&ws[r * 256 + tx], __ATOMIC_RELAXED,
                                                 __HIP_MEMORY_SCOPE_AGENT);
            if (c < K_ORD) flag = (uint32_t)tx;
        }
#pragma unroll
        for (int off = 32; off > 0; off >>= 1) {
            const uint32_t o = __shfl_down(flag, off, 64);
            flag = flag < o ? flag : o;
        }
        if ((tx & 63) == 0) sh[tx >> 6] = flag;
        __syncthreads();
        // only waves 0..3 hold tx<256; higher waves wrote 1024 (ignored)
        const uint32_t cs = min(min(sh[0], sh[1]), min(sh[2], sh[3]));
        __syncthreads();   // protect sh before reuse (next round / caller)
        fstar = __hip_atomic_load(&ws[r * 256 + cs], __ATOMIC_RELAXED,
                                  __HIP_MEMORY_SCOPE_AGENT);
        const uint64_t W = (uint64_t)(hi - lo);
        const uint32_t Tc = lo + (uint32_t)(((uint64_t)(cs + 1) * W) >> 8);
        if (cs > 0) lo = lo + (uint32_t)(((uint64_t)cs * W) >> 8) + 1u;
        hi = Tc;
    }
}

// Kernels 2-4: rounds 1-3. Wave-shfl sum-reduce (1 barrier vs 9); partial
// accumulated into the probe's single slot via device-scope atomicAdd.
template <int ROUND>
__global__ void __launch_bounds__(512) select_round_kernel(uint32_t* __restrict__ ws) {
    __shared__ float ps[NN];
    __shared__ uint32_t sh[8];
    const int tx = threadIdx.x;
    const int bx = blockIdx.x;
    for (int t = tx; t < NN / 4; t += 512)
        reinterpret_cast<float4*>(ps)[t] =
            reinterpret_cast<const float4*>(ws + WS_SORT)[t];
    __syncthreads();
    uint32_t lo, hi, fs;
    bracket_chain<512>(ws, ROUND - 1, sh, lo, hi, fs);
    const uint64_t W = (uint64_t)(hi - lo);
    const uint32_t T = lo + (uint32_t)(((uint64_t)((bx >> 2) + 1) * W) >> 8);
    uint32_t v = eval_count4(ps, T, (bx & 3) * 2048);
#pragma unroll
    for (int off = 32; off > 0; off >>= 1) v += __shfl_down(v, off, 64);
    if ((tx & 63) == 0) sh[tx >> 6] = v;
    __syncthreads();
    if (tx == 0) {
        uint32_t s = 0;
#pragma unroll
        for (int w = 0; w < 8; ++w) s += sh[w];
        atomicAdd(&ws[(ROUND - 1) * 256 + (bx >> 2)], s);  // device-scope (m20)
    }
}

// Kernel 5: streamed 268MB mask write, nontemporal float4 stores. Bracket is
// recomputed per block from the compacted partials (3KB L2-resident reads,
// hidden under store BW) — finalize kernel eliminated.
__global__ void __launch_bounds__(256) mask_kernel(const float* __restrict__ p,
                                                   float* __restrict__ out,
                                                   uint32_t* __restrict__ ws) {
    __shared__ uint32_t sh[8];
    uint32_t lo, hi, fs;
    bracket_chain<256>(ws, 3, sh, lo, hi, fs);
    const int tx = threadIdx.x;
    const int i = blockIdx.y;
    const int jb0 = blockIdx.x * 4096;
    const float pi = p[i];
    const size_t rowbase = (size_t)i * NN;
#pragma unroll
    for (int q = 0; q < 4; ++q) {
        const int j = jb0 + q * 1024 + tx * 4;
        const float4 pj = *reinterpret_cast<const float4*>(p + j);
        const float pjv[4] = {pj.x, pj.y, pj.z, pj.w};
        float vv[4];
#pragma unroll
        for (int c = 0; c < 4; ++c) {
            const int jj = j + c;
            float v = 0.0f;
            if (jj != i) {
                const uint32_t key = fkey(pi * pjv[c]);
                if (key > hi) {
                    v = 1.0f;
                } else if (key >= lo) {
                    const uint32_t pos = atomicAdd(&ws[WS_TIECNT], 1u);
                    if (pos < TIE_CAP)
                        reinterpret_cast<uint2*>(ws + WS_TIE)[pos] =
                            make_uint2(key, (uint32_t)(i * NN + jj));
                }
            }
            vv[c] = v;
        }
        f32x4 o;
        o.x = vv[0]; o.y = vv[1]; o.z = vv[2]; o.w = vv[3];
        __builtin_nontemporal_store(o,
            reinterpret_cast<f32x4*>(out + rowbase + j));
    }
}

// Kernel 6: among the n in-bracket entries set the top r by (key desc, flat
// idx asc) to 1.0 — exactly jax.lax.top_k's ordering. Bracket recomputed
// in-block (finalize eliminated); r = K - f(hi).
__global__ void __launch_bounds__(256) tie_select_kernel(float* __restrict__ out,
                                                         uint32_t* __restrict__ ws) {
    __shared__ uint32_t sh[8];
    uint32_t lo, hi, fs;
    bracket_chain<256>(ws, 3, sh, lo, hi, fs);
    const uint32_t r = K_ORD - fs;
    uint32_t n = ws[WS_TIECNT];
    if (n > TIE_CAP) n = TIE_CAP;
    const uint2* buf = reinterpret_cast<const uint2*>(ws + WS_TIE);
    for (uint32_t e = threadIdx.x; e < n; e += 256) {
        const uint2 me = buf[e];
        uint32_t rank = 0;
        for (uint32_t m = 0; m < n; ++m) {
            const uint2 o = buf[m];
            rank += ((o.x > me.x) || (o.x == me.x && o.y < me.y)) ? 1u : 0u;
        }
        if (rank < r) out[me.y] = 1.0f;
    }
}

extern "C" void kernel_launch(void* const* d_in, const int* in_sizes, int n_in,
                              void* d_out, int out_size, void* d_ws, size_t ws_size,
                              hipStream_t stream) {
    const float* p = (const float*)d_in[0];
    float* out = (float*)d_out;
    uint32_t* ws = (uint32_t*)d_ws;

    sort_kernel<<<1024, 256, 0, stream>>>(p, ws);
    select_round_kernel<1><<<1024, 512, 0, stream>>>(ws);
    select_round_kernel<2><<<1024, 512, 0, stream>>>(ws);
    select_round_kernel<3><<<1024, 512, 0, stream>>>(ws);
    mask_kernel<<<dim3(2, NN), 256, 0, stream>>>(p, out, ws);
    tie_select_kernel<<<1, 256, 0, stream>>>(out, ws);
}